// Round 14
// baseline (84.185 us; speedup 1.0000x reference)
//
#include <hip/hip_runtime.h>
#include <hip/hip_bf16.h>

// ---------------------------------------------------------------------------
// Fused SiamCAR head, Round 16: R12 trunk + FUSED tower chunk loop.
// Grid 512, 512 thr, 64KB, 2 blocks/CU, 1 round. Every wave keeps R12's
// per-wave geometry but each chunk phase does BOTH towers' work:
//   {pw_cls + pw_box} barrier {stage x4 | pred_cls + pred_box} barrier
// -> 16 loop barriers instead of 32; phases fatter (latency-bound absorbs).
// Pre-loop: dw_cls -> bfr_cls -> dw_box -> bfr_box with NO barriers
// (d_T strictly wave-local, proven R13); corr A dies before the loop.
// Arch-register audit vs the 64-arch split: bfr 32 + transients 8 + addr ~12
// = ~56-60 < 64 (accw/accp in acc file). R8/R9 failed at 96+.
// LDS: corr phase as R12. Tower phase:
//   feat_cls 0-16K | feat_box 16-32K | pw_cls dbuf 32-40K | pw_box 40-48K |
//   wA_cls dbuf @49152 (2x576) | wA_box @50304 (2x2304) | BN @54912..59008
// ---------------------------------------------------------------------------

typedef __attribute__((ext_vector_type(8))) short  bf16x8;
typedef __attribute__((ext_vector_type(4))) float  f32x4;

union U8 { bf16x8 v; uint4 q; unsigned short u[8]; };

__device__ __forceinline__ float bf2f(unsigned short h){
  union { unsigned int u; float f; } c; c.u = ((unsigned int)h) << 16; return c.f;
}
__device__ __forceinline__ unsigned short f2bf(float f){
  return __bfloat16_as_ushort(__float2bfloat16(f));   // HW cvt, RNE
}
__device__ __forceinline__ unsigned int f2bf2(float lo, float hi){
  return (unsigned int)f2bf(lo) | ((unsigned int)f2bf(hi) << 16);
}

// corr A tile [64 p][256 pix] bf16, elem index, 16B-chunk XOR swizzle.
__device__ __forceinline__ int swz(int row, int pix){
  return row*256 + (((pix>>3) ^ (row&31))<<3) + (pix&7);
}
// z^T tile [64 p][128 c] bf16, byte offset (256B rows, 16 chunks XOR by p).
__device__ __forceinline__ int zt_off(int p, int c){
  return (p<<8) + ((((c>>3) ^ (p&15)) & 15)<<4) + ((c&7)<<1);
}
// search^T chunk [256 pix][64 c] bf16, byte offset (128B rows, 8 chunks).
__device__ __forceinline__ int sT_off(int pix, int c){
  return (pix<<7) + ((((c>>3) ^ (pix&7) ^ ((pix>>3)&7)) & 7)<<4) + ((c&7)<<1);
}
// d_T [256 pix][64 p] bf16, byte offset.
__device__ __forceinline__ int dT_off(int pix, int p){
  return (pix<<7) + (((((p>>3) ^ pix) & 7)) << 4) + ((p & 7) << 1);
}
// feat_T [256 pix][32 ocl] bf16, byte offset (within a 16K buffer).
__device__ __forceinline__ int fT_off(int pix, int ocl){
  return (pix<<6) + ((((ocl>>3) ^ pix ^ (pix>>2)) & 3) << 4) + ((ocl & 7) << 1);
}
// pw A-tile [32 ocl][64 p] bf16, byte offset.
__device__ __forceinline__ int pA_off(int ocl, int p){
  return (ocl<<7) + (((((p>>3) ^ ocl) & 7)) << 4) + ((p & 7) << 1);
}

// stage one 32-oc chunk of pw (fp32 global) -> [32][64] bf16 swizzled (512 thr)
__device__ __forceinline__ void stage_pw(int tid, int oc0,
                                         const float* __restrict__ pw,
                                         unsigned char* __restrict__ dst){
  const int ocl = tid >> 4, p0 = (tid & 15) << 2;
  const float4 f0 = *(const float4*)&pw[(oc0 + ocl)*64 + p0];
  uint2 w; w.x = f2bf2(f0.x, f0.y); w.y = f2bf2(f0.z, f0.w);
  *(uint2*)(dst + pA_off(ocl, p0)) = w;
}

// stage pred weights for one oc-chunk: wA[o][k = tau*32 + ocl] bf16 (512 thr)
template<int NOUT>
__device__ __forceinline__ void stage_wA(int tid, int oc0,
                                         const float* __restrict__ pdw,
                                         unsigned char* __restrict__ dst){
  #pragma unroll
  for (int i=0;i<(NOUT*288+511)/512;++i){
    const int idx = i*512 + tid;
    if (idx < NOUT*288){
      const int o   = idx / 288;
      const int rem = idx - o*288;
      const int tau = rem >> 5, ocl = rem & 31;
      *(unsigned short*)(dst + (idx<<1)) =
          f2bf(pdw[(o*256 + oc0 + ocl)*9 + tau]);
    }
  }
}

// depthwise 3x3 (pad 1), attention folded; wave owns rows 2w..2w+1; writes
// ONLY its own d_T slice (pixels [32w,32w+32)) — wave-local, no barrier.
__device__ __forceinline__ void dw_phase(
    int lane, int wave, float ap, const float* __restrict__ dw,
    const unsigned short* __restrict__ sA16, unsigned char* __restrict__ dT)
{
  const int p = lane;
  float wd[9];
  #pragma unroll
  for (int k=0;k<9;++k) wd[k] = dw[p*9+k] * ap;
  #pragma unroll
  for (int io=0;io<2;++io){
    const int ir = wave*2 + io;
    float ot[16];
    #pragma unroll
    for (int j=0;j<16;++j) ot[j] = 0.f;
    #pragma unroll
    for (int dr=0;dr<3;++dr){
      const int r = ir-1+dr;
      if (r >= 0 && r < 16){
        unsigned short tr[16];
        *(uint4*)&tr[0] = *(uint4*)&sA16[swz(p, r*16)];
        *(uint4*)&tr[8] = *(uint4*)&sA16[swz(p, r*16 + 8)];
        float rr[16];
        #pragma unroll
        for (int j=0;j<16;++j) rr[j] = bf2f(tr[j]);
        const float w0 = wd[dr*3+0], w1 = wd[dr*3+1], w2 = wd[dr*3+2];
        #pragma unroll
        for (int j=0;j<16;++j){
          float s = w1*rr[j];
          if (j > 0)  s = fmaf(w0, rr[j-1], s);
          if (j < 15) s = fmaf(w2, rr[j+1], s);
          ot[j] += s;
        }
      }
    }
    #pragma unroll
    for (int j=0;j<16;++j)
      *(unsigned short*)(dT + dT_off(ir*16+j, p)) = f2bf(ot[j]);
  }
}

// pointwise chunk (mt-sequential, fused BN): feat[32oc x 256pix] slice
__device__ __forceinline__ void pw_phase(
    int l15, int lg, int wave, const U8 bfr[2][2],
    const unsigned char* __restrict__ pAb, unsigned char* __restrict__ featb,
    const float* __restrict__ scl, const float* __restrict__ bia, int oc0)
{
  #pragma unroll
  for (int mt=0;mt<2;++mt){
    U8 af0, af1;
    af0.q = *(const uint4*)(pAb + pA_off(mt*16 + l15, lg*8));
    af1.q = *(const uint4*)(pAb + pA_off(mt*16 + l15, 32 + lg*8));
    f32x4 accw[2];
    accw[0] = f32x4{0.f,0.f,0.f,0.f};
    accw[1] = f32x4{0.f,0.f,0.f,0.f};
    #pragma unroll
    for (int nt=0;nt<2;++nt){
      accw[nt] = __builtin_amdgcn_mfma_f32_16x16x32_bf16(
          af0.v, bfr[nt][0].v, accw[nt], 0, 0, 0);
      accw[nt] = __builtin_amdgcn_mfma_f32_16x16x32_bf16(
          af1.v, bfr[nt][1].v, accw[nt], 0, 0, 0);
    }
    #pragma unroll
    for (int r=0;r<4;++r){
      const int ocl = mt*16 + lg*4 + r;
      const float sc = scl[oc0+ocl], bi = bia[oc0+ocl];
      #pragma unroll
      for (int nt=0;nt<2;++nt){
        const int pix = wave*32 + nt*16 + l15;
        const float v = fmaxf(fmaf(accw[nt][r], sc, bi), 0.f);
        *(unsigned short*)(featb + fT_off(pix, ocl)) = f2bf(v);
      }
    }
  }
}

// pred 3x3 partial via MFMA for one chunk
template<int NOUT>
__device__ __forceinline__ void pred_phase(
    int l15, int lg, int wave,
    const unsigned char* __restrict__ featb,
    const unsigned char* __restrict__ wAb, f32x4* accp)
{
  #pragma unroll
  for (int dr=0;dr<3;++dr){
    #pragma unroll
    for (int dc=0;dc<3;++dc){
      const int tau = dr*3 + dc;
      U8 a;
      const int mr = (NOUT == 4) ? (l15 & 3) : 0;
      a.q = *(const uint4*)(wAb + ((mr*288 + tau*32 + lg*8) << 1));
      if (l15 >= NOUT) a.q = make_uint4(0u,0u,0u,0u);
      #pragma unroll
      for (int nt=0;nt<2;++nt){
        const int rp = wave*2 + nt + dr - 1;      // uniform per wave
        if (rp >= 0 && rp <= 15){
          const int cp = l15 + dc - 1;
          const int cc = cp < 0 ? 0 : (cp > 15 ? 15 : cp);
          U8 bf;
          bf.q = *(const uint4*)(featb + fT_off(rp*16 + cc, lg*8));
          if (cp != cc) bf.q = make_uint4(0u,0u,0u,0u);
          accp[nt] = __builtin_amdgcn_mfma_f32_16x16x32_bf16(
              a.v, bf.v, accp[nt], 0, 0, 0);
        }
      }
    }
  }
}

__global__ __launch_bounds__(512, 4) void fused_head(
  const float* __restrict__ search, const float* __restrict__ kern,
  const float* __restrict__ ca_w1, const float* __restrict__ ca_b1,
  const float* __restrict__ ca_w2, const float* __restrict__ ca_b2,
  const float* __restrict__ cls_dw, const float* __restrict__ cls_pw,
  const float* __restrict__ cls_bn_g, const float* __restrict__ cls_bn_b,
  const float* __restrict__ cls_bn_m, const float* __restrict__ cls_bn_v,
  const float* __restrict__ cls_pred_w, const float* __restrict__ cls_pred_b,
  const float* __restrict__ box_dw, const float* __restrict__ box_pw,
  const float* __restrict__ box_bn_g, const float* __restrict__ box_bn_b,
  const float* __restrict__ box_bn_m, const float* __restrict__ box_bn_v,
  const float* __restrict__ box_pred_w, const float* __restrict__ box_pred_b,
  const float* __restrict__ adjust, const float* __restrict__ bias_p,
  float* __restrict__ out)
{
  __shared__ __align__(16) unsigned char smem[65536];
  const int b   = blockIdx.x;               // grid 512: one block per batch
  const int tid = threadIdx.x;
  const int lane = tid & 63, wave = tid >> 6;     // 8 waves
  const int l15 = lane & 15, lg = lane >> 4;

  // ---- stage z^T single-bf16 [64 p][128 c] swizzled @0 (16KB)
  unsigned char* zb = smem;
  {
    const float* kb = kern + (size_t)b*7168;       // [112 c][64 p]
    #pragma unroll
    for (int i=0;i<14;++i){
      const int idx = i*512 + tid;
      const int c = idx>>6, p = idx&63;
      *(unsigned short*)(zb + zt_off(p,c)) = f2bf(kb[idx]);
    }
    #pragma unroll
    for (int i=0;i<2;++i){                         // zero-pad c in [112,128)
      const int idx = i*512 + tid;
      const int p = idx>>4, c = 112 + (idx&15);
      *(unsigned short*)(zb + zt_off(p,c)) = 0;
    }
  }

  // ---- corr via MFMA: corr[64 p][256 pix] = z^T(64x112) * search(112x256)
  unsigned char* stb = smem + 16384;       // search^T chunk [256][64] bf16
  const float* sea = search + (size_t)b*28672;
  f32x4 acc[4][2];
  #pragma unroll
  for (int mt=0;mt<4;++mt)
    #pragma unroll
    for (int nt=0;nt<2;++nt) acc[mt][nt] = f32x4{0.f,0.f,0.f,0.f};

  for (int kc=0;kc<2;++kc){
    __syncthreads();                       // stb free (or z staging done)
    #pragma unroll
    for (int i=0;i<8;++i){
      const int f4i = i*512 + tid;
      const int cc = f4i>>6, pix0 = (f4i&63)<<2;
      const int c  = kc*64 + cc;
      float4 v;
      if (c < 112) v = *(const float4*)(sea + c*256 + pix0);
      else         v = make_float4(0.f,0.f,0.f,0.f);
      const float vv[4] = {v.x, v.y, v.z, v.w};
      #pragma unroll
      for (int j=0;j<4;++j)
        *(unsigned short*)(stb + sT_off(pix0+j, cc)) = f2bf(vv[j]);
    }
    __syncthreads();                       // chunk staged
    #pragma unroll
    for (int kt=0;kt<2;++kt){
      U8 bh[2];
      #pragma unroll
      for (int nt=0;nt<2;++nt){
        const int pix = wave*32 + nt*16 + l15;
        bh[nt].q = *(const uint4*)(stb + sT_off(pix, kt*32 + lg*8));
      }
      #pragma unroll
      for (int mt=0;mt<4;++mt){
        U8 ah;
        ah.q = *(const uint4*)(zb + zt_off(mt*16 + l15, kc*64 + kt*32 + lg*8));
        #pragma unroll
        for (int nt=0;nt<2;++nt)
          acc[mt][nt] = __builtin_amdgcn_mfma_f32_16x16x32_bf16(
              ah.v, bh[nt].v, acc[mt][nt], 0, 0, 0);
      }
    }
  }
  __syncthreads();                         // all LDS reads of z/stb drained

  // ---- stage corr UNSCALED bf16 [64][256] swizzled @0 (acc dies after MLP)
  unsigned short* sA16 = (unsigned short*)smem;
  #pragma unroll
  for (int mt=0;mt<4;++mt){
    #pragma unroll
    for (int nt=0;nt<2;++nt){
      const int pix = wave*32 + nt*16 + l15;
      #pragma unroll
      for (int r=0;r<4;++r)
        sA16[swz(mt*16 + lg*4 + r, pix)] = f2bf(acc[mt][nt][r]);
    }
  }

  // ---- row sums -> means + channel-attention MLP (scratch @49152; dead
  //      before the towers overwrite it — barrier after ap hoist)
  float* ws    = (float*)(smem + 49152);          // [8][64] = 2048 B
  float* smean = (float*)(smem + 51200);          // 64 f32
  float* h1    = (float*)(smem + 51456);          // 64 f32
  float* attvG = (float*)(smem + 51712);          // 64 f32
  #pragma unroll
  for (int mt=0;mt<4;++mt){
    #pragma unroll
    for (int r=0;r<4;++r){
      float s = acc[mt][0][r] + acc[mt][1][r];
      s += __shfl_xor(s, 1, 64);
      s += __shfl_xor(s, 2, 64);
      s += __shfl_xor(s, 4, 64);
      s += __shfl_xor(s, 8, 64);
      if (l15 == 0) ws[wave*64 + mt*16 + lg*4 + r] = s;
    }
  }
  __syncthreads();
  if (tid < 64){
    float m = 0.f;
    #pragma unroll
    for (int w=0;w<8;++w) m += ws[w*64 + tid];
    smean[tid] = m * (1.f/256.f);
  }
  __syncthreads();
  if (tid < 64){
    float s = ca_b1[tid];
    const float* wr = ca_w1 + tid*64;
    #pragma unroll 8
    for (int k=0;k<64;++k) s += smean[k]*wr[k];
    h1[tid] = fmaxf(s, 0.f);
  }
  __syncthreads();
  if (tid < 64){
    float s = ca_b2[tid];
    const float* wr = ca_w2 + tid*64;
    #pragma unroll 8
    for (int k=0;k<64;++k) s += h1[k]*wr[k];
    attvG[tid] = 1.f/(1.f + expf(-s));
  }
  __syncthreads();               // attv ready
  const float ap = attvG[lane];
  __syncthreads();               // attv reads done before d_T clobbers @49152

  const float adj = adjust[0];

  // ---- both depthwises + bfr caches, all wave-local on d_T: NO barriers
  unsigned char* dT = smem + 32768;
  U8 bfr_cls[2][2], bfr_box[2][2];
  dw_phase(lane, wave, ap, cls_dw, sA16, dT);
  #pragma unroll
  for (int nt=0;nt<2;++nt)
    #pragma unroll
    for (int ks=0;ks<2;++ks)
      bfr_cls[nt][ks].q = *(const uint4*)(dT +
          dT_off(wave*32 + nt*16 + l15, ks*32 + lg*8));
  dw_phase(lane, wave, ap, box_dw, sA16, dT);
  #pragma unroll
  for (int nt=0;nt<2;++nt)
    #pragma unroll
    for (int ks=0;ks<2;++ks)
      bfr_box[nt][ks].q = *(const uint4*)(dT +
          dT_off(wave*32 + nt*16 + l15, ks*32 + lg*8));
  __syncthreads();   // all bfr done; corr A + d_T dead; all LDS free

  // ---- BN tables (both towers) + chunk-0 staging
  float* sclc = (float*)(smem + 54912);      // cls scale 256 f32
  float* biac = (float*)(smem + 55936);      // cls bias  256 f32
  float* sclb = (float*)(smem + 56960);      // box scale 256 f32
  float* biab = (float*)(smem + 57984);      // box bias  256 f32
  if (tid < 256){
    float s = cls_bn_g[tid] * rsqrtf(cls_bn_v[tid] + 1e-5f);
    sclc[tid] = s; biac[tid] = cls_bn_b[tid] - cls_bn_m[tid]*s;
    s = box_bn_g[tid] * rsqrtf(box_bn_v[tid] + 1e-5f);
    sclb[tid] = s; biab[tid] = box_bn_b[tid] - box_bn_m[tid]*s;
  }
  stage_pw(tid, 0, cls_pw, smem + 32768);
  stage_pw(tid, 0, box_pw, smem + 40960);
  stage_wA<1>(tid, 0, cls_pred_w, smem + 49152);
  stage_wA<4>(tid, 0, box_pred_w, smem + 50304);

  f32x4 apc[2], apb[2];
  apc[0] = f32x4{0.f,0.f,0.f,0.f}; apc[1] = f32x4{0.f,0.f,0.f,0.f};
  apb[0] = f32x4{0.f,0.f,0.f,0.f}; apb[1] = f32x4{0.f,0.f,0.f,0.f};

  // ---- FUSED chunk loop: both towers per phase, 2 barriers per chunk
  for (int ch=0; ch<8; ++ch){
    const int buf = ch & 1, oc0 = ch*32;
    __syncthreads();   // staged bufs ready; prev preds done reading feats

    pw_phase(l15, lg, wave, bfr_cls, smem + 32768 + buf*4096,
             smem + 0,     sclc, biac, oc0);
    pw_phase(l15, lg, wave, bfr_box, smem + 40960 + buf*4096,
             smem + 16384, sclb, biab, oc0);
    __syncthreads();   // feats ready

    if (ch < 7){       // stage next chunk (slots' readers ran >=1 barrier ago)
      stage_pw(tid, oc0 + 32, cls_pw, smem + 32768 + (buf^1)*4096);
      stage_pw(tid, oc0 + 32, box_pw, smem + 40960 + (buf^1)*4096);
      stage_wA<1>(tid, oc0 + 32, cls_pred_w, smem + 49152 + (buf^1)*576);
      stage_wA<4>(tid, oc0 + 32, box_pred_w, smem + 50304 + (buf^1)*2304);
    }
    pred_phase<1>(l15, lg, wave, smem + 0,     smem + 49152 + buf*576,  apc);
    pred_phase<4>(l15, lg, wave, smem + 16384, smem + 50304 + buf*2304, apb);
  }

  // ---- epilogue: lanes 0-15 hold out-chs in regs; wave covers rows 2w..2w+1
  if (lane < 16){
    #pragma unroll
    for (int nt=0;nt<2;++nt){
      const int rt = wave*2 + nt;
      out[524288 + (size_t)b*256 + rt*16 + lane] =
          0.1f*(apc[nt][0] + cls_pred_b[0]);
      #pragma unroll
      for (int o=0;o<4;++o)
        out[(size_t)b*1024 + o*256 + rt*16 + lane] =
            expf(fmaf(adj, apb[nt][o] + box_pred_b[o], bias_p[o]));
    }
  }
}

extern "C" void kernel_launch(void* const* d_in, const int* in_sizes, int n_in,
                              void* d_out, int out_size, void* d_ws, size_t ws_size,
                              hipStream_t stream) {
  (void)in_sizes; (void)n_in; (void)d_ws; (void)ws_size; (void)out_size;
  const float* search     = (const float*)d_in[0];
  const float* kern       = (const float*)d_in[1];
  const float* ca_w1      = (const float*)d_in[2];
  const float* ca_b1      = (const float*)d_in[3];
  const float* ca_w2      = (const float*)d_in[4];
  const float* ca_b2      = (const float*)d_in[5];
  const float* cls_dw     = (const float*)d_in[6];
  const float* cls_pw     = (const float*)d_in[7];
  const float* cls_bn_g   = (const float*)d_in[8];
  const float* cls_bn_b   = (const float*)d_in[9];
  const float* cls_bn_m   = (const float*)d_in[10];
  const float* cls_bn_v   = (const float*)d_in[11];
  const float* cls_pred_w = (const float*)d_in[12];
  const float* cls_pred_b = (const float*)d_in[13];
  const float* box_dw     = (const float*)d_in[14];
  const float* box_pw     = (const float*)d_in[15];
  const float* box_bn_g   = (const float*)d_in[16];
  const float* box_bn_b   = (const float*)d_in[17];
  const float* box_bn_m   = (const float*)d_in[18];
  const float* box_bn_v   = (const float*)d_in[19];
  const float* box_pred_w = (const float*)d_in[20];
  const float* box_pred_b = (const float*)d_in[21];
  const float* adjust     = (const float*)d_in[22];
  const float* bias_p     = (const float*)d_in[23];

  hipLaunchKernelGGL(fused_head, dim3(512), dim3(512), 0, stream,
    search, kern, ca_w1, ca_b1, ca_w2, ca_b2,
    cls_dw, cls_pw, cls_bn_g, cls_bn_b, cls_bn_m, cls_bn_v,
    cls_pred_w, cls_pred_b,
    box_dw, box_pw, box_bn_g, box_bn_b, box_bn_m, box_bn_v,
    box_pred_w, box_pred_b, adjust, bias_p,
    (float*)d_out);
}

// Round 15
// 78.583 us; speedup vs baseline: 1.0713x; 1.0713x over previous
//
#include <hip/hip_runtime.h>
#include <hip/hip_bf16.h>

// ---------------------------------------------------------------------------
// Fused SiamCAR head, Round 17: R12 trunk (68.5us best: grid 512, 512 thr,
// 64KB, sequential towers, 2-barrier chunk loop, native bf16 cvt, no spill)
// + all-lane redundant channel-attention MLP:
//   old: 4 serial tid<64 phases + ap hoist = 5 barriers, 7/8 waves idle
//   new: 1 barrier (ws visibility) then every wave computes the 64-ch MLP
//        via __shfl dot products (identical summation order -> bitwise same);
//        ap lands directly in a register.
// + d_T-complete barrier removed in towers (wave-local; proven R13).
// Net: ~6 fewer barriers, zero added register pressure (R14's lesson: fatter
// phases that add live registers lose; this adds only transients).
// ---------------------------------------------------------------------------

typedef __attribute__((ext_vector_type(8))) short  bf16x8;
typedef __attribute__((ext_vector_type(4))) float  f32x4;

union U8 { bf16x8 v; uint4 q; unsigned short u[8]; };

__device__ __forceinline__ float bf2f(unsigned short h){
  union { unsigned int u; float f; } c; c.u = ((unsigned int)h) << 16; return c.f;
}
__device__ __forceinline__ unsigned short f2bf(float f){
  return __bfloat16_as_ushort(__float2bfloat16(f));   // HW cvt, RNE
}
__device__ __forceinline__ unsigned int f2bf2(float lo, float hi){
  return (unsigned int)f2bf(lo) | ((unsigned int)f2bf(hi) << 16);
}

// corr A tile [64 p][256 pix] bf16, elem index, 16B-chunk XOR swizzle.
__device__ __forceinline__ int swz(int row, int pix){
  return row*256 + (((pix>>3) ^ (row&31))<<3) + (pix&7);
}
// z^T tile [64 p][128 c] bf16, byte offset (256B rows, 16 chunks XOR by p).
__device__ __forceinline__ int zt_off(int p, int c){
  return (p<<8) + ((((c>>3) ^ (p&15)) & 15)<<4) + ((c&7)<<1);
}
// search^T chunk [256 pix][64 c] bf16, byte offset (128B rows, 8 chunks).
__device__ __forceinline__ int sT_off(int pix, int c){
  return (pix<<7) + ((((c>>3) ^ (pix&7) ^ ((pix>>3)&7)) & 7)<<4) + ((c&7)<<1);
}
// d_T [256 pix][64 p] bf16, byte offset.
__device__ __forceinline__ int dT_off(int pix, int p){
  return (pix<<7) + (((((p>>3) ^ pix) & 7)) << 4) + ((p & 7) << 1);
}
// feat_T [256 pix][32 ocl] bf16, byte offset.
__device__ __forceinline__ int fT_off(int pix, int ocl){
  return (pix<<6) + ((((ocl>>3) ^ pix ^ (pix>>2)) & 3) << 4) + ((ocl & 7) << 1);
}
// pw A-tile [32 ocl][64 p] bf16, byte offset.
__device__ __forceinline__ int pA_off(int ocl, int p){
  return (ocl<<7) + (((((p>>3) ^ ocl) & 7)) << 4) + ((p & 7) << 1);
}

// stage one 32-oc chunk of pw (fp32 global) -> [32][64] bf16 swizzled (512 thr)
__device__ __forceinline__ void stage_pw(int tid, int oc0,
                                         const float* __restrict__ pw,
                                         unsigned char* __restrict__ dst){
  const int ocl = tid >> 4, p0 = (tid & 15) << 2;
  const float4 f0 = *(const float4*)&pw[(oc0 + ocl)*64 + p0];
  uint2 w; w.x = f2bf2(f0.x, f0.y); w.y = f2bf2(f0.z, f0.w);
  *(uint2*)(dst + pA_off(ocl, p0)) = w;
}

// stage pred weights for one oc-chunk: wA[o][k = tau*32 + ocl] bf16 (512 thr)
template<int NOUT>
__device__ __forceinline__ void stage_wA(int tid, int oc0,
                                         const float* __restrict__ pdw,
                                         unsigned char* __restrict__ dst){
  #pragma unroll
  for (int i=0;i<(NOUT*288+511)/512;++i){
    const int idx = i*512 + tid;
    if (idx < NOUT*288){
      const int o   = idx / 288;
      const int rem = idx - o*288;
      const int tau = rem >> 5, ocl = rem & 31;
      *(unsigned short*)(dst + (idx<<1)) =
          f2bf(pdw[(o*256 + oc0 + ocl)*9 + tau]);
    }
  }
}

template<int NOUT>
__device__ __forceinline__ void run_tower(
    int tid, float ap,
    const float* __restrict__ dw,  const float* __restrict__ pw,
    const float* __restrict__ bng, const float* __restrict__ bnb,
    const float* __restrict__ bnm, const float* __restrict__ bnv,
    const float* __restrict__ pdw, const float* __restrict__ pdb,
    float* __restrict__ outp, float adj, const float* __restrict__ biasp,
    unsigned char* smem)
{
  const int lane = tid & 63, wave = tid >> 6;      // 8 waves
  const int l15 = lane & 15, lg = lane >> 4;
  unsigned short* sA16 = (unsigned short*)smem;    // corr A [64][256], RO

  // ---- depthwise 3x3 (pad 1), attention folded into weights, streamed;
  //      wave owns image rows 2w..2w+1; writes ONLY its own d_T slice
  //      (pixels [32w,32w+32)) -> wave-local, no barrier needed after
  {
    const int p = lane;
    unsigned char* dT = smem + 32768;
    float wd[9];
    #pragma unroll
    for (int k=0;k<9;++k) wd[k] = dw[p*9+k] * ap;
    #pragma unroll
    for (int io=0;io<2;++io){
      const int ir = wave*2 + io;
      float ot[16];
      #pragma unroll
      for (int j=0;j<16;++j) ot[j] = 0.f;
      #pragma unroll
      for (int dr=0;dr<3;++dr){
        const int r = ir-1+dr;
        if (r >= 0 && r < 16){
          unsigned short tr[16];
          *(uint4*)&tr[0] = *(uint4*)&sA16[swz(p, r*16)];
          *(uint4*)&tr[8] = *(uint4*)&sA16[swz(p, r*16 + 8)];
          float rr[16];
          #pragma unroll
          for (int j=0;j<16;++j) rr[j] = bf2f(tr[j]);
          const float w0 = wd[dr*3+0], w1 = wd[dr*3+1], w2 = wd[dr*3+2];
          #pragma unroll
          for (int j=0;j<16;++j){
            float s = w1*rr[j];
            if (j > 0)  s = fmaf(w0, rr[j-1], s);
            if (j < 15) s = fmaf(w2, rr[j+1], s);
            ot[j] += s;
          }
        }
      }
      #pragma unroll
      for (int j=0;j<16;++j)
        *(unsigned short*)(dT + dT_off(ir*16+j, p)) = f2bf(ot[j]);
    }
  }
  // NO barrier: bfr below reads only this wave's own d_T slice (same-wave
  // LDS write->read ordered by program order + compiler lgkmcnt). [R13]

  // ---- pointwise B-operand chunk-invariant: cache wave's 32 pix in 16 VGPRs
  U8 bfr[2][2];
  #pragma unroll
  for (int nt=0;nt<2;++nt)
    #pragma unroll
    for (int ks=0;ks<2;++ks)
      bfr[nt][ks].q = *(const uint4*)(smem + 32768 +
          dT_off(wave*32 + nt*16 + l15, ks*32 + lg*8));
  __syncthreads();   // ALL waves' bfr done; d_T region reusable

  // ---- BN scale/bias tables + chunk-0 weight staging
  float* scl = (float*)(smem + 61952);       // 256 f32
  float* bia = (float*)(smem + 62976);       // 256 f32
  if (tid < 256){
    const float s = bng[tid] * rsqrtf(bnv[tid] + 1e-5f);
    scl[tid] = s;
    bia[tid] = bnb[tid] - bnm[tid]*s;
  }
  stage_pw(tid, 0, pw, smem + 49152);
  stage_wA<NOUT>(tid, 0, pdw, smem + 57344);

  // pred accumulators: wave owns image rows 2w..2w+1; lane<16 reg r = out ch
  f32x4 accp[2];
  #pragma unroll
  for (int nt=0;nt<2;++nt) accp[nt] = f32x4{0.f,0.f,0.f,0.f};

  for (int ch=0; ch<8; ++ch){
    const int buf = ch & 1, oc0 = ch*32;
    __syncthreads();   // staged buf ready; prev pred finished reading feat_T

    // ---- pointwise via MFMA: feat[32 oc][256 pix] = pw(32x64) * d(64x256)
    unsigned char* pAb = smem + 49152 + buf*4096;
    U8 af[2][2];
    #pragma unroll
    for (int mt=0;mt<2;++mt)
      #pragma unroll
      for (int ks=0;ks<2;++ks)
        af[mt][ks].q = *(const uint4*)(pAb + pA_off(mt*16 + l15, ks*32 + lg*8));
    f32x4 accw[2][2];
    #pragma unroll
    for (int mt=0;mt<2;++mt)
      #pragma unroll
      for (int nt=0;nt<2;++nt) accw[mt][nt] = f32x4{0.f,0.f,0.f,0.f};
    #pragma unroll
    for (int nt=0;nt<2;++nt){
      #pragma unroll
      for (int mt=0;mt<2;++mt){
        accw[mt][nt] = __builtin_amdgcn_mfma_f32_16x16x32_bf16(
            af[mt][0].v, bfr[nt][0].v, accw[mt][nt], 0, 0, 0);
        accw[mt][nt] = __builtin_amdgcn_mfma_f32_16x16x32_bf16(
            af[mt][1].v, bfr[nt][1].v, accw[mt][nt], 0, 0, 0);
      }
    }
    // BN + ReLU -> feat_T [pix][32 ocl] bf16 @32768
    #pragma unroll
    for (int mt=0;mt<2;++mt){
      #pragma unroll
      for (int r=0;r<4;++r){
        const int ocl = mt*16 + lg*4 + r;
        const float sc = scl[oc0+ocl], bi = bia[oc0+ocl];
        #pragma unroll
        for (int nt=0;nt<2;++nt){
          const int pix = wave*32 + nt*16 + l15;
          const float v = fmaxf(fmaf(accw[mt][nt][r], sc, bi), 0.f);
          *(unsigned short*)(smem + 32768 + fT_off(pix, ocl)) = f2bf(v);
        }
      }
    }
    __syncthreads();   // feat_T chunk ready

    // ---- pred 3x3 partial via MFMA
    unsigned char* wAb = smem + 57344 + buf*2304;
    #pragma unroll
    for (int dr=0;dr<3;++dr){
      #pragma unroll
      for (int dc=0;dc<3;++dc){
        const int tau = dr*3 + dc;
        U8 a;
        const int mr = (NOUT == 4) ? (l15 & 3) : 0;
        a.q = *(const uint4*)(wAb + ((mr*288 + tau*32 + lg*8) << 1));
        if (l15 >= NOUT) a.q = make_uint4(0u,0u,0u,0u);
        #pragma unroll
        for (int nt=0;nt<2;++nt){
          const int rp = wave*2 + nt + dr - 1;      // uniform per wave
          if (rp >= 0 && rp <= 15){
            const int cp = l15 + dc - 1;
            const int cc = cp < 0 ? 0 : (cp > 15 ? 15 : cp);
            U8 bf;
            bf.q = *(const uint4*)(smem + 32768 + fT_off(rp*16 + cc, lg*8));
            if (cp != cc) bf.q = make_uint4(0u,0u,0u,0u);
            accp[nt] = __builtin_amdgcn_mfma_f32_16x16x32_bf16(
                a.v, bf.v, accp[nt], 0, 0, 0);
          }
        }
      }
    }
    // stage next chunk's weights (writes buf^1; no reader this phase)
    if (ch < 7){
      stage_pw(tid, oc0 + 32, pw, smem + 49152 + (buf^1)*4096);
      stage_wA<NOUT>(tid, oc0 + 32, pdw, smem + 57344 + (buf^1)*2304);
    }
  }

  // ---- epilogue: lanes 0-15 hold out-chs in regs; wave covers rows 2w..2w+1
  if (lane < 16){
    #pragma unroll
    for (int nt=0;nt<2;++nt){
      const int rt = wave*2 + nt;
      if constexpr (NOUT == 1){
        outp[rt*16 + lane] = 0.1f*(accp[nt][0] + pdb[0]);
      } else {
        #pragma unroll
        for (int o=0;o<4;++o)
          outp[o*256 + rt*16 + lane] =
              expf(fmaf(adj, accp[nt][o] + pdb[o], biasp[o]));
      }
    }
  }
  __syncthreads();   // feat_T/weight reads done before next tower's d_T write
}

__global__ __launch_bounds__(512, 4) void fused_head(
  const float* __restrict__ search, const float* __restrict__ kern,
  const float* __restrict__ ca_w1, const float* __restrict__ ca_b1,
  const float* __restrict__ ca_w2, const float* __restrict__ ca_b2,
  const float* __restrict__ cls_dw, const float* __restrict__ cls_pw,
  const float* __restrict__ cls_bn_g, const float* __restrict__ cls_bn_b,
  const float* __restrict__ cls_bn_m, const float* __restrict__ cls_bn_v,
  const float* __restrict__ cls_pred_w, const float* __restrict__ cls_pred_b,
  const float* __restrict__ box_dw, const float* __restrict__ box_pw,
  const float* __restrict__ box_bn_g, const float* __restrict__ box_bn_b,
  const float* __restrict__ box_bn_m, const float* __restrict__ box_bn_v,
  const float* __restrict__ box_pred_w, const float* __restrict__ box_pred_b,
  const float* __restrict__ adjust, const float* __restrict__ bias_p,
  float* __restrict__ out)
{
  __shared__ __align__(16) unsigned char smem[65536];
  const int b   = blockIdx.x;               // grid 512: one block per batch
  const int tid = threadIdx.x;
  const int lane = tid & 63, wave = tid >> 6;     // 8 waves
  const int l15 = lane & 15, lg = lane >> 4;

  // ---- stage z^T single-bf16 [64 p][128 c] swizzled @0 (16KB)
  unsigned char* zb = smem;
  {
    const float* kb = kern + (size_t)b*7168;       // [112 c][64 p]
    #pragma unroll
    for (int i=0;i<14;++i){
      const int idx = i*512 + tid;
      const int c = idx>>6, p = idx&63;
      *(unsigned short*)(zb + zt_off(p,c)) = f2bf(kb[idx]);
    }
    #pragma unroll
    for (int i=0;i<2;++i){                         // zero-pad c in [112,128)
      const int idx = i*512 + tid;
      const int p = idx>>4, c = 112 + (idx&15);
      *(unsigned short*)(zb + zt_off(p,c)) = 0;
    }
  }

  // ---- corr via MFMA: corr[64 p][256 pix] = z^T(64x112) * search(112x256)
  unsigned char* stb = smem + 16384;       // search^T chunk [256][64] bf16
  const float* sea = search + (size_t)b*28672;
  f32x4 acc[4][2];
  #pragma unroll
  for (int mt=0;mt<4;++mt)
    #pragma unroll
    for (int nt=0;nt<2;++nt) acc[mt][nt] = f32x4{0.f,0.f,0.f,0.f};

  for (int kc=0;kc<2;++kc){
    __syncthreads();                       // stb free (or z staging done)
    #pragma unroll
    for (int i=0;i<8;++i){
      const int f4i = i*512 + tid;
      const int cc = f4i>>6, pix0 = (f4i&63)<<2;
      const int c  = kc*64 + cc;
      float4 v;
      if (c < 112) v = *(const float4*)(sea + c*256 + pix0);
      else         v = make_float4(0.f,0.f,0.f,0.f);
      const float vv[4] = {v.x, v.y, v.z, v.w};
      #pragma unroll
      for (int j=0;j<4;++j)
        *(unsigned short*)(stb + sT_off(pix0+j, cc)) = f2bf(vv[j]);
    }
    __syncthreads();                       // chunk staged
    #pragma unroll
    for (int kt=0;kt<2;++kt){
      U8 bh[2];
      #pragma unroll
      for (int nt=0;nt<2;++nt){
        const int pix = wave*32 + nt*16 + l15;
        bh[nt].q = *(const uint4*)(stb + sT_off(pix, kt*32 + lg*8));
      }
      #pragma unroll
      for (int mt=0;mt<4;++mt){
        U8 ah;
        ah.q = *(const uint4*)(zb + zt_off(mt*16 + l15, kc*64 + kt*32 + lg*8));
        #pragma unroll
        for (int nt=0;nt<2;++nt)
          acc[mt][nt] = __builtin_amdgcn_mfma_f32_16x16x32_bf16(
              ah.v, bh[nt].v, acc[mt][nt], 0, 0, 0);
      }
    }
  }
  __syncthreads();                         // all LDS reads of z/stb drained

  // ---- stage corr UNSCALED bf16 [64][256] swizzled @0 (acc dies after MLP)
  unsigned short* sA16 = (unsigned short*)smem;
  #pragma unroll
  for (int mt=0;mt<4;++mt){
    #pragma unroll
    for (int nt=0;nt<2;++nt){
      const int pix = wave*32 + nt*16 + l15;
      #pragma unroll
      for (int r=0;r<4;++r)
        sA16[swz(mt*16 + lg*4 + r, pix)] = f2bf(acc[mt][nt][r]);
    }
  }

  // ---- row sums -> ws; ONE barrier; then ALL-LANE redundant MLP via shfl
  // (identical summation order as the old tid<64 version -> bitwise same)
  float* ws = (float*)(smem + 49152);             // [8][64] = 2048 B
  #pragma unroll
  for (int mt=0;mt<4;++mt){
    #pragma unroll
    for (int r=0;r<4;++r){
      float s = acc[mt][0][r] + acc[mt][1][r];
      s += __shfl_xor(s, 1, 64);
      s += __shfl_xor(s, 2, 64);
      s += __shfl_xor(s, 4, 64);
      s += __shfl_xor(s, 8, 64);
      if (l15 == 0) ws[wave*64 + mt*16 + lg*4 + r] = s;
    }
  }
  __syncthreads();                                // ws visible to all waves

  float ap;
  {
    float m = 0.f;
    #pragma unroll
    for (int w=0;w<8;++w) m += ws[w*64 + lane];
    const float smean_r = m * (1.f/256.f);        // lane's channel mean

    float s1 = ca_b1[lane];
    const float* wr1 = ca_w1 + lane*64;
    #pragma unroll 8
    for (int k=0;k<64;++k) s1 += __shfl(smean_r, k, 64) * wr1[k];
    const float h1_r = fmaxf(s1, 0.f);

    float s2 = ca_b2[lane];
    const float* wr2 = ca_w2 + lane*64;
    #pragma unroll 8
    for (int k=0;k<64;++k) s2 += __shfl(h1_r, k, 64) * wr2[k];
    ap = 1.f/(1.f + expf(-s2));                   // attv for channel = lane
  }
  // No barrier needed: ws reads are per-thread program-order before any LDS
  // write below; first write to @49152+ is tower staging, which sits after
  // the tower's internal bfr barrier.

  const float adj = adjust[0];

  run_tower<1>(tid, ap, cls_dw, cls_pw, cls_bn_g, cls_bn_b, cls_bn_m,
               cls_bn_v, cls_pred_w, cls_pred_b,
               out + 524288 + (size_t)b*256, adj, bias_p, smem);
  run_tower<4>(tid, ap, box_dw, box_pw, box_bn_g, box_bn_b, box_bn_m,
               box_bn_v, box_pred_w, box_pred_b,
               out + (size_t)b*1024, adj, bias_p, smem);
}

extern "C" void kernel_launch(void* const* d_in, const int* in_sizes, int n_in,
                              void* d_out, int out_size, void* d_ws, size_t ws_size,
                              hipStream_t stream) {
  (void)in_sizes; (void)n_in; (void)d_ws; (void)ws_size; (void)out_size;
  const float* search     = (const float*)d_in[0];
  const float* kern       = (const float*)d_in[1];
  const float* ca_w1      = (const float*)d_in[2];
  const float* ca_b1      = (const float*)d_in[3];
  const float* ca_w2      = (const float*)d_in[4];
  const float* ca_b2      = (const float*)d_in[5];
  const float* cls_dw     = (const float*)d_in[6];
  const float* cls_pw     = (const float*)d_in[7];
  const float* cls_bn_g   = (const float*)d_in[8];
  const float* cls_bn_b   = (const float*)d_in[9];
  const float* cls_bn_m   = (const float*)d_in[10];
  const float* cls_bn_v   = (const float*)d_in[11];
  const float* cls_pred_w = (const float*)d_in[12];
  const float* cls_pred_b = (const float*)d_in[13];
  const float* box_dw     = (const float*)d_in[14];
  const float* box_pw     = (const float*)d_in[15];
  const float* box_bn_g   = (const float*)d_in[16];
  const float* box_bn_b   = (const float*)d_in[17];
  const float* box_bn_m   = (const float*)d_in[18];
  const float* box_bn_v   = (const float*)d_in[19];
  const float* box_pred_w = (const float*)d_in[20];
  const float* box_pred_b = (const float*)d_in[21];
  const float* adjust     = (const float*)d_in[22];
  const float* bias_p     = (const float*)d_in[23];

  hipLaunchKernelGGL(fused_head, dim3(512), dim3(512), 0, stream,
    search, kern, ca_w1, ca_b1, ca_w2, ca_b2,
    cls_dw, cls_pw, cls_bn_g, cls_bn_b, cls_bn_m, cls_bn_v,
    cls_pred_w, cls_pred_b,
    box_dw, box_pw, box_bn_g, box_bn_b, box_bn_m, box_bn_v,
    box_pred_w, box_pred_b, adjust, bias_p,
    (float*)d_out);
}

// Round 16
// 73.667 us; speedup vs baseline: 1.1428x; 1.0667x over previous
//
#include <hip/hip_runtime.h>
#include <hip/hip_bf16.h>

// ---------------------------------------------------------------------------
// Fused SiamCAR head, Round 18: R12 trunk (68.5us best) + straight-line
// feat DOUBLE-buffer pipeline for the BOX tower only (runs last; corr A is
// dead after its depthwise, freeing 0-32K for feat[0]/feat[1]).
//   box loop: {stage pw(i+2)->slot(i&1) | stage wA(i+1)->wslot(~i&1) |
//              pw_chunk(i+1)->feat[~i&1] | pred(i)<-feat[i&1],wslot(i&1)}
//              -> ONE barrier/chunk (9 barriers vs 16).
// R11's DBUF spilled via lambda capture; this is lambda-free straight-line
// (R12-style), adding only loop-parity address offsets (~2 transient regs).
// cls tower: exact R12 2-barrier loop (corr A must survive it).
// d_T-complete barrier dropped in both towers (wave-local; proven R13).
// MLP: R12's tid<64 version (R15's all-lane variant regressed: uncoalesced
// weight-row reads x8 waves).
// ---------------------------------------------------------------------------

typedef __attribute__((ext_vector_type(8))) short  bf16x8;
typedef __attribute__((ext_vector_type(4))) float  f32x4;

union U8 { bf16x8 v; uint4 q; unsigned short u[8]; };

__device__ __forceinline__ float bf2f(unsigned short h){
  union { unsigned int u; float f; } c; c.u = ((unsigned int)h) << 16; return c.f;
}
__device__ __forceinline__ unsigned short f2bf(float f){
  return __bfloat16_as_ushort(__float2bfloat16(f));   // HW cvt, RNE
}
__device__ __forceinline__ unsigned int f2bf2(float lo, float hi){
  return (unsigned int)f2bf(lo) | ((unsigned int)f2bf(hi) << 16);
}

// corr A tile [64 p][256 pix] bf16, elem index, 16B-chunk XOR swizzle.
__device__ __forceinline__ int swz(int row, int pix){
  return row*256 + (((pix>>3) ^ (row&31))<<3) + (pix&7);
}
// z^T tile [64 p][128 c] bf16, byte offset (256B rows, 16 chunks XOR by p).
__device__ __forceinline__ int zt_off(int p, int c){
  return (p<<8) + ((((c>>3) ^ (p&15)) & 15)<<4) + ((c&7)<<1);
}
// search^T chunk [256 pix][64 c] bf16, byte offset (128B rows, 8 chunks).
__device__ __forceinline__ int sT_off(int pix, int c){
  return (pix<<7) + ((((c>>3) ^ (pix&7) ^ ((pix>>3)&7)) & 7)<<4) + ((c&7)<<1);
}
// d_T [256 pix][64 p] bf16, byte offset.
__device__ __forceinline__ int dT_off(int pix, int p){
  return (pix<<7) + (((((p>>3) ^ pix) & 7)) << 4) + ((p & 7) << 1);
}
// feat_T [256 pix][32 ocl] bf16, byte offset (within a 16K buffer).
__device__ __forceinline__ int fT_off(int pix, int ocl){
  return (pix<<6) + ((((ocl>>3) ^ pix ^ (pix>>2)) & 3) << 4) + ((ocl & 7) << 1);
}
// pw A-tile [32 ocl][64 p] bf16, byte offset.
__device__ __forceinline__ int pA_off(int ocl, int p){
  return (ocl<<7) + (((((p>>3) ^ ocl) & 7)) << 4) + ((p & 7) << 1);
}

// stage one 32-oc chunk of pw (fp32 global) -> [32][64] bf16 swizzled (512 thr)
__device__ __forceinline__ void stage_pw(int tid, int oc0,
                                         const float* __restrict__ pw,
                                         unsigned char* __restrict__ dst){
  const int ocl = tid >> 4, p0 = (tid & 15) << 2;
  const float4 f0 = *(const float4*)&pw[(oc0 + ocl)*64 + p0];
  uint2 w; w.x = f2bf2(f0.x, f0.y); w.y = f2bf2(f0.z, f0.w);
  *(uint2*)(dst + pA_off(ocl, p0)) = w;
}

// stage pred weights for one oc-chunk: wA[o][k = tau*32 + ocl] bf16 (512 thr)
template<int NOUT>
__device__ __forceinline__ void stage_wA(int tid, int oc0,
                                         const float* __restrict__ pdw,
                                         unsigned char* __restrict__ dst){
  #pragma unroll
  for (int i=0;i<(NOUT*288+511)/512;++i){
    const int idx = i*512 + tid;
    if (idx < NOUT*288){
      const int o   = idx / 288;
      const int rem = idx - o*288;
      const int tau = rem >> 5, ocl = rem & 31;
      *(unsigned short*)(dst + (idx<<1)) =
          f2bf(pdw[(o*256 + oc0 + ocl)*9 + tau]);
    }
  }
}

// ---- cls tower: exact R12 structure (2-barrier chunk loop) ----------------
__device__ __forceinline__ void run_tower_cls(
    int tid, float ap,
    const float* __restrict__ dw,  const float* __restrict__ pw,
    const float* __restrict__ bng, const float* __restrict__ bnb,
    const float* __restrict__ bnm, const float* __restrict__ bnv,
    const float* __restrict__ pdw, const float* __restrict__ pdb,
    float* __restrict__ outp, unsigned char* smem)
{
  const int lane = tid & 63, wave = tid >> 6;
  const int l15 = lane & 15, lg = lane >> 4;
  unsigned short* sA16 = (unsigned short*)smem;    // corr A, RO

  // depthwise -> d_T @32768 (wave-local slice; no barrier after — R13)
  {
    const int p = lane;
    unsigned char* dT = smem + 32768;
    float wd[9];
    #pragma unroll
    for (int k=0;k<9;++k) wd[k] = dw[p*9+k] * ap;
    #pragma unroll
    for (int io=0;io<2;++io){
      const int ir = wave*2 + io;
      float ot[16];
      #pragma unroll
      for (int j=0;j<16;++j) ot[j] = 0.f;
      #pragma unroll
      for (int dr=0;dr<3;++dr){
        const int r = ir-1+dr;
        if (r >= 0 && r < 16){
          unsigned short tr[16];
          *(uint4*)&tr[0] = *(uint4*)&sA16[swz(p, r*16)];
          *(uint4*)&tr[8] = *(uint4*)&sA16[swz(p, r*16 + 8)];
          float rr[16];
          #pragma unroll
          for (int j=0;j<16;++j) rr[j] = bf2f(tr[j]);
          const float w0 = wd[dr*3+0], w1 = wd[dr*3+1], w2 = wd[dr*3+2];
          #pragma unroll
          for (int j=0;j<16;++j){
            float s = w1*rr[j];
            if (j > 0)  s = fmaf(w0, rr[j-1], s);
            if (j < 15) s = fmaf(w2, rr[j+1], s);
            ot[j] += s;
          }
        }
      }
      #pragma unroll
      for (int j=0;j<16;++j)
        *(unsigned short*)(dT + dT_off(ir*16+j, p)) = f2bf(ot[j]);
    }
  }
  U8 bfr[2][2];
  #pragma unroll
  for (int nt=0;nt<2;++nt)
    #pragma unroll
    for (int ks=0;ks<2;++ks)
      bfr[nt][ks].q = *(const uint4*)(smem + 32768 +
          dT_off(wave*32 + nt*16 + l15, ks*32 + lg*8));
  __syncthreads();   // all bfr done; d_T reusable

  float* scl = (float*)(smem + 61952);
  float* bia = (float*)(smem + 62976);
  if (tid < 256){
    const float s = bng[tid] * rsqrtf(bnv[tid] + 1e-5f);
    scl[tid] = s;
    bia[tid] = bnb[tid] - bnm[tid]*s;
  }
  stage_pw(tid, 0, pw, smem + 49152);
  stage_wA<1>(tid, 0, pdw, smem + 57344);

  f32x4 accp[2];
  accp[0] = f32x4{0.f,0.f,0.f,0.f};
  accp[1] = f32x4{0.f,0.f,0.f,0.f};

  for (int ch=0; ch<8; ++ch){
    const int buf = ch & 1, oc0 = ch*32;
    __syncthreads();
    unsigned char* pAb = smem + 49152 + buf*4096;
    #pragma unroll
    for (int mt=0;mt<2;++mt){
      U8 af0, af1;
      af0.q = *(const uint4*)(pAb + pA_off(mt*16 + l15, lg*8));
      af1.q = *(const uint4*)(pAb + pA_off(mt*16 + l15, 32 + lg*8));
      f32x4 aw0 = f32x4{0.f,0.f,0.f,0.f};
      f32x4 aw1 = f32x4{0.f,0.f,0.f,0.f};
      aw0 = __builtin_amdgcn_mfma_f32_16x16x32_bf16(af0.v, bfr[0][0].v, aw0, 0,0,0);
      aw0 = __builtin_amdgcn_mfma_f32_16x16x32_bf16(af1.v, bfr[0][1].v, aw0, 0,0,0);
      aw1 = __builtin_amdgcn_mfma_f32_16x16x32_bf16(af0.v, bfr[1][0].v, aw1, 0,0,0);
      aw1 = __builtin_amdgcn_mfma_f32_16x16x32_bf16(af1.v, bfr[1][1].v, aw1, 0,0,0);
      #pragma unroll
      for (int r=0;r<4;++r){
        const int ocl = mt*16 + lg*4 + r;
        const float sc = scl[oc0+ocl], bi = bia[oc0+ocl];
        *(unsigned short*)(smem + 32768 + fT_off(wave*32 + l15, ocl)) =
            f2bf(fmaxf(fmaf(aw0[r], sc, bi), 0.f));
        *(unsigned short*)(smem + 32768 + fT_off(wave*32 + 16 + l15, ocl)) =
            f2bf(fmaxf(fmaf(aw1[r], sc, bi), 0.f));
      }
    }
    __syncthreads();
    unsigned char* wAb = smem + 57344 + buf*576;
    #pragma unroll
    for (int dr=0;dr<3;++dr){
      #pragma unroll
      for (int dc=0;dc<3;++dc){
        const int tau = dr*3 + dc;
        U8 a;
        a.q = *(const uint4*)(wAb + ((tau*32 + lg*8) << 1));
        if (l15 >= 1) a.q = make_uint4(0u,0u,0u,0u);
        #pragma unroll
        for (int nt=0;nt<2;++nt){
          const int rp = wave*2 + nt + dr - 1;
          if (rp >= 0 && rp <= 15){
            const int cp = l15 + dc - 1;
            const int cc = cp < 0 ? 0 : (cp > 15 ? 15 : cp);
            U8 bf;
            bf.q = *(const uint4*)(smem + 32768 + fT_off(rp*16 + cc, lg*8));
            if (cp != cc) bf.q = make_uint4(0u,0u,0u,0u);
            accp[nt] = __builtin_amdgcn_mfma_f32_16x16x32_bf16(
                a.v, bf.v, accp[nt], 0, 0, 0);
          }
        }
      }
    }
    if (ch < 7){
      stage_pw(tid, oc0 + 32, pw, smem + 49152 + (buf^1)*4096);
      stage_wA<1>(tid, oc0 + 32, pdw, smem + 57344 + (buf^1)*576);
    }
  }

  if (lane < 16){
    #pragma unroll
    for (int nt=0;nt<2;++nt){
      const int rt = wave*2 + nt;
      outp[rt*16 + lane] = 0.1f*(accp[nt][0] + pdb[0]);
    }
  }
  __syncthreads();   // all feat/weight reads done before box tower's d_T
}

// ---- box tower: straight-line feat DOUBLE-buffer, 1 barrier/chunk ---------
__device__ __forceinline__ void run_tower_box(
    int tid, float ap,
    const float* __restrict__ dw,  const float* __restrict__ pw,
    const float* __restrict__ bng, const float* __restrict__ bnb,
    const float* __restrict__ bnm, const float* __restrict__ bnv,
    const float* __restrict__ pdw, const float* __restrict__ pdb,
    float* __restrict__ outp, float adj, const float* __restrict__ biasp,
    unsigned char* smem)
{
  const int lane = tid & 63, wave = tid >> 6;
  const int l15 = lane & 15, lg = lane >> 4;
  unsigned short* sA16 = (unsigned short*)smem;    // corr A (dies after dw)

  // depthwise -> d_T @32768 (wave-local; no barrier — R13)
  {
    const int p = lane;
    unsigned char* dT = smem + 32768;
    float wd[9];
    #pragma unroll
    for (int k=0;k<9;++k) wd[k] = dw[p*9+k] * ap;
    #pragma unroll
    for (int io=0;io<2;++io){
      const int ir = wave*2 + io;
      float ot[16];
      #pragma unroll
      for (int j=0;j<16;++j) ot[j] = 0.f;
      #pragma unroll
      for (int dr=0;dr<3;++dr){
        const int r = ir-1+dr;
        if (r >= 0 && r < 16){
          unsigned short tr[16];
          *(uint4*)&tr[0] = *(uint4*)&sA16[swz(p, r*16)];
          *(uint4*)&tr[8] = *(uint4*)&sA16[swz(p, r*16 + 8)];
          float rr[16];
          #pragma unroll
          for (int j=0;j<16;++j) rr[j] = bf2f(tr[j]);
          const float w0 = wd[dr*3+0], w1 = wd[dr*3+1], w2 = wd[dr*3+2];
          #pragma unroll
          for (int j=0;j<16;++j){
            float s = w1*rr[j];
            if (j > 0)  s = fmaf(w0, rr[j-1], s);
            if (j < 15) s = fmaf(w2, rr[j+1], s);
            ot[j] += s;
          }
        }
      }
      #pragma unroll
      for (int j=0;j<16;++j)
        *(unsigned short*)(dT + dT_off(ir*16+j, p)) = f2bf(ot[j]);
    }
  }
  U8 bfr[2][2];
  #pragma unroll
  for (int nt=0;nt<2;++nt)
    #pragma unroll
    for (int ks=0;ks<2;++ks)
      bfr[nt][ks].q = *(const uint4*)(smem + 32768 +
          dT_off(wave*32 + nt*16 + l15, ks*32 + lg*8));
  __syncthreads();   // all dw reads of corr A + bfr done; 0-64K free

  // BN tables + prologue staging: pw0->slot0, pw1->slot1, wA0->wslot0
  float* scl = (float*)(smem + 61952);
  float* bia = (float*)(smem + 62976);
  if (tid < 256){
    const float s = bng[tid] * rsqrtf(bnv[tid] + 1e-5f);
    scl[tid] = s;
    bia[tid] = bnb[tid] - bnm[tid]*s;
  }
  stage_pw(tid, 0,  pw, smem + 49152);
  stage_pw(tid, 32, pw, smem + 53248);
  stage_wA<4>(tid, 0, pdw, smem + 57344);
  __syncthreads();   // staging + BN visible

  f32x4 accp[2];
  accp[0] = f32x4{0.f,0.f,0.f,0.f};
  accp[1] = f32x4{0.f,0.f,0.f,0.f};

  // prologue: pw_chunk(0) from slot0 -> feat[0] @0
  {
    unsigned char* pAb = smem + 49152;
    #pragma unroll
    for (int mt=0;mt<2;++mt){
      U8 af0, af1;
      af0.q = *(const uint4*)(pAb + pA_off(mt*16 + l15, lg*8));
      af1.q = *(const uint4*)(pAb + pA_off(mt*16 + l15, 32 + lg*8));
      f32x4 aw0 = f32x4{0.f,0.f,0.f,0.f};
      f32x4 aw1 = f32x4{0.f,0.f,0.f,0.f};
      aw0 = __builtin_amdgcn_mfma_f32_16x16x32_bf16(af0.v, bfr[0][0].v, aw0, 0,0,0);
      aw0 = __builtin_amdgcn_mfma_f32_16x16x32_bf16(af1.v, bfr[0][1].v, aw0, 0,0,0);
      aw1 = __builtin_amdgcn_mfma_f32_16x16x32_bf16(af0.v, bfr[1][0].v, aw1, 0,0,0);
      aw1 = __builtin_amdgcn_mfma_f32_16x16x32_bf16(af1.v, bfr[1][1].v, aw1, 0,0,0);
      #pragma unroll
      for (int r=0;r<4;++r){
        const int ocl = mt*16 + lg*4 + r;
        const float sc = scl[ocl], bi = bia[ocl];
        *(unsigned short*)(smem + fT_off(wave*32 + l15, ocl)) =
            f2bf(fmaxf(fmaf(aw0[r], sc, bi), 0.f));
        *(unsigned short*)(smem + fT_off(wave*32 + 16 + l15, ocl)) =
            f2bf(fmaxf(fmaf(aw1[r], sc, bi), 0.f));
      }
    }
  }
  __syncthreads();   // feat[0] visible

  // pipelined loop: ONE barrier per chunk
  for (int i=0; i<8; ++i){
    const int par = i & 1;
    // stage pw(i+2) -> pw slot par (read by pw_chunk(i) last iter; barrier'd)
    if (i < 6) stage_pw(tid, (i+2)*32, pw, smem + 49152 + par*4096);
    // stage wA(i+1) -> wslot par^1 (read by pred(i-1) last iter; barrier'd)
    if (i < 7) stage_wA<4>(tid, (i+1)*32, pdw, smem + 57344 + (par^1)*2304);
    // pw_chunk(i+1): reads pw slot par^1 -> feat[par^1]
    if (i < 7){
      unsigned char* pAb   = smem + 49152 + (par^1)*4096;
      unsigned char* featw = smem + ((par^1)<<14);
      const int oc0 = (i+1)*32;
      #pragma unroll
      for (int mt=0;mt<2;++mt){
        U8 af0, af1;
        af0.q = *(const uint4*)(pAb + pA_off(mt*16 + l15, lg*8));
        af1.q = *(const uint4*)(pAb + pA_off(mt*16 + l15, 32 + lg*8));
        f32x4 aw0 = f32x4{0.f,0.f,0.f,0.f};
        f32x4 aw1 = f32x4{0.f,0.f,0.f,0.f};
        aw0 = __builtin_amdgcn_mfma_f32_16x16x32_bf16(af0.v, bfr[0][0].v, aw0, 0,0,0);
        aw0 = __builtin_amdgcn_mfma_f32_16x16x32_bf16(af1.v, bfr[0][1].v, aw0, 0,0,0);
        aw1 = __builtin_amdgcn_mfma_f32_16x16x32_bf16(af0.v, bfr[1][0].v, aw1, 0,0,0);
        aw1 = __builtin_amdgcn_mfma_f32_16x16x32_bf16(af1.v, bfr[1][1].v, aw1, 0,0,0);
        #pragma unroll
        for (int r=0;r<4;++r){
          const int ocl = mt*16 + lg*4 + r;
          const float sc = scl[oc0+ocl], bi = bia[oc0+ocl];
          *(unsigned short*)(featw + fT_off(wave*32 + l15, ocl)) =
              f2bf(fmaxf(fmaf(aw0[r], sc, bi), 0.f));
          *(unsigned short*)(featw + fT_off(wave*32 + 16 + l15, ocl)) =
              f2bf(fmaxf(fmaf(aw1[r], sc, bi), 0.f));
        }
      }
    }
    // pred(i): reads feat[par] and wslot par
    {
      unsigned char* featr = smem + (par<<14);
      unsigned char* wAb   = smem + 57344 + par*2304;
      #pragma unroll
      for (int dr=0;dr<3;++dr){
        #pragma unroll
        for (int dc=0;dc<3;++dc){
          const int tau = dr*3 + dc;
          U8 a;
          a.q = *(const uint4*)(wAb + (((l15&3)*288 + tau*32 + lg*8) << 1));
          if (l15 >= 4) a.q = make_uint4(0u,0u,0u,0u);
          #pragma unroll
          for (int nt=0;nt<2;++nt){
            const int rp = wave*2 + nt + dr - 1;
            if (rp >= 0 && rp <= 15){
              const int cp = l15 + dc - 1;
              const int cc = cp < 0 ? 0 : (cp > 15 ? 15 : cp);
              U8 bf;
              bf.q = *(const uint4*)(featr + fT_off(rp*16 + cc, lg*8));
              if (cp != cc) bf.q = make_uint4(0u,0u,0u,0u);
              accp[nt] = __builtin_amdgcn_mfma_f32_16x16x32_bf16(
                  a.v, bf.v, accp[nt], 0, 0, 0);
            }
          }
        }
      }
    }
    __syncthreads();
  }

  // epilogue
  if (lane < 16){
    #pragma unroll
    for (int nt=0;nt<2;++nt){
      const int rt = wave*2 + nt;
      #pragma unroll
      for (int o=0;o<4;++o)
        outp[o*256 + rt*16 + lane] =
            expf(fmaf(adj, accp[nt][o] + pdb[o], biasp[o]));
    }
  }
}

__global__ __launch_bounds__(512, 4) void fused_head(
  const float* __restrict__ search, const float* __restrict__ kern,
  const float* __restrict__ ca_w1, const float* __restrict__ ca_b1,
  const float* __restrict__ ca_w2, const float* __restrict__ ca_b2,
  const float* __restrict__ cls_dw, const float* __restrict__ cls_pw,
  const float* __restrict__ cls_bn_g, const float* __restrict__ cls_bn_b,
  const float* __restrict__ cls_bn_m, const float* __restrict__ cls_bn_v,
  const float* __restrict__ cls_pred_w, const float* __restrict__ cls_pred_b,
  const float* __restrict__ box_dw, const float* __restrict__ box_pw,
  const float* __restrict__ box_bn_g, const float* __restrict__ box_bn_b,
  const float* __restrict__ box_bn_m, const float* __restrict__ box_bn_v,
  const float* __restrict__ box_pred_w, const float* __restrict__ box_pred_b,
  const float* __restrict__ adjust, const float* __restrict__ bias_p,
  float* __restrict__ out)
{
  __shared__ __align__(16) unsigned char smem[65536];
  const int b   = blockIdx.x;               // grid 512: one block per batch
  const int tid = threadIdx.x;
  const int lane = tid & 63, wave = tid >> 6;     // 8 waves
  const int l15 = lane & 15, lg = lane >> 4;

  // ---- stage z^T single-bf16 [64 p][128 c] swizzled @0 (16KB)
  unsigned char* zb = smem;
  {
    const float* kb = kern + (size_t)b*7168;       // [112 c][64 p]
    #pragma unroll
    for (int i=0;i<14;++i){
      const int idx = i*512 + tid;
      const int c = idx>>6, p = idx&63;
      *(unsigned short*)(zb + zt_off(p,c)) = f2bf(kb[idx]);
    }
    #pragma unroll
    for (int i=0;i<2;++i){                         // zero-pad c in [112,128)
      const int idx = i*512 + tid;
      const int p = idx>>4, c = 112 + (idx&15);
      *(unsigned short*)(zb + zt_off(p,c)) = 0;
    }
  }

  // ---- corr via MFMA: corr[64 p][256 pix] = z^T(64x112) * search(112x256)
  unsigned char* stb = smem + 16384;       // search^T chunk [256][64] bf16
  const float* sea = search + (size_t)b*28672;
  f32x4 acc[4][2];
  #pragma unroll
  for (int mt=0;mt<4;++mt)
    #pragma unroll
    for (int nt=0;nt<2;++nt) acc[mt][nt] = f32x4{0.f,0.f,0.f,0.f};

  for (int kc=0;kc<2;++kc){
    __syncthreads();                       // stb free (or z staging done)
    #pragma unroll
    for (int i=0;i<8;++i){
      const int f4i = i*512 + tid;
      const int cc = f4i>>6, pix0 = (f4i&63)<<2;
      const int c  = kc*64 + cc;
      float4 v;
      if (c < 112) v = *(const float4*)(sea + c*256 + pix0);
      else         v = make_float4(0.f,0.f,0.f,0.f);
      const float vv[4] = {v.x, v.y, v.z, v.w};
      #pragma unroll
      for (int j=0;j<4;++j)
        *(unsigned short*)(stb + sT_off(pix0+j, cc)) = f2bf(vv[j]);
    }
    __syncthreads();                       // chunk staged
    #pragma unroll
    for (int kt=0;kt<2;++kt){
      U8 bh[2];
      #pragma unroll
      for (int nt=0;nt<2;++nt){
        const int pix = wave*32 + nt*16 + l15;
        bh[nt].q = *(const uint4*)(stb + sT_off(pix, kt*32 + lg*8));
      }
      #pragma unroll
      for (int mt=0;mt<4;++mt){
        U8 ah;
        ah.q = *(const uint4*)(zb + zt_off(mt*16 + l15, kc*64 + kt*32 + lg*8));
        #pragma unroll
        for (int nt=0;nt<2;++nt)
          acc[mt][nt] = __builtin_amdgcn_mfma_f32_16x16x32_bf16(
              ah.v, bh[nt].v, acc[mt][nt], 0, 0, 0);
      }
    }
  }
  __syncthreads();                         // all LDS reads of z/stb drained

  // ---- stage corr UNSCALED bf16 [64][256] swizzled @0 (acc dies after MLP)
  unsigned short* sA16 = (unsigned short*)smem;
  #pragma unroll
  for (int mt=0;mt<4;++mt){
    #pragma unroll
    for (int nt=0;nt<2;++nt){
      const int pix = wave*32 + nt*16 + l15;
      #pragma unroll
      for (int r=0;r<4;++r)
        sA16[swz(mt*16 + lg*4 + r, pix)] = f2bf(acc[mt][nt][r]);
    }
  }

  // ---- row sums -> means + channel-attention MLP (R12's tid<64 version)
  float* ws    = (float*)(smem + 49152);          // [8][64] = 2048 B
  float* smean = (float*)(smem + 51200);          // 64 f32
  float* h1    = (float*)(smem + 51456);          // 64 f32
  float* attvG = (float*)(smem + 51712);          // 64 f32
  #pragma unroll
  for (int mt=0;mt<4;++mt){
    #pragma unroll
    for (int r=0;r<4;++r){
      float s = acc[mt][0][r] + acc[mt][1][r];
      s += __shfl_xor(s, 1, 64);
      s += __shfl_xor(s, 2, 64);
      s += __shfl_xor(s, 4, 64);
      s += __shfl_xor(s, 8, 64);
      if (l15 == 0) ws[wave*64 + mt*16 + lg*4 + r] = s;
    }
  }
  __syncthreads();
  if (tid < 64){
    float m = 0.f;
    #pragma unroll
    for (int w=0;w<8;++w) m += ws[w*64 + tid];
    smean[tid] = m * (1.f/256.f);
  }
  __syncthreads();
  if (tid < 64){
    float s = ca_b1[tid];
    const float* wr = ca_w1 + tid*64;
    #pragma unroll 8
    for (int k=0;k<64;++k) s += smean[k]*wr[k];
    h1[tid] = fmaxf(s, 0.f);
  }
  __syncthreads();
  if (tid < 64){
    float s = ca_b2[tid];
    const float* wr = ca_w2 + tid*64;
    #pragma unroll 8
    for (int k=0;k<64;++k) s += h1[k]*wr[k];
    attvG[tid] = 1.f/(1.f + expf(-s));
  }
  __syncthreads();               // attv ready
  const float ap = attvG[lane];
  __syncthreads();               // attv reads done before towers reuse @49152

  const float adj = adjust[0];

  run_tower_cls(tid, ap, cls_dw, cls_pw, cls_bn_g, cls_bn_b, cls_bn_m,
                cls_bn_v, cls_pred_w, cls_pred_b,
                out + 524288 + (size_t)b*256, smem);
  run_tower_box(tid, ap, box_dw, box_pw, box_bn_g, box_bn_b, box_bn_m,
                box_bn_v, box_pred_w, box_pred_b,
                out + (size_t)b*1024, adj, bias_p, smem);
}

extern "C" void kernel_launch(void* const* d_in, const int* in_sizes, int n_in,
                              void* d_out, int out_size, void* d_ws, size_t ws_size,
                              hipStream_t stream) {
  (void)in_sizes; (void)n_in; (void)d_ws; (void)ws_size; (void)out_size;
  const float* search     = (const float*)d_in[0];
  const float* kern       = (const float*)d_in[1];
  const float* ca_w1      = (const float*)d_in[2];
  const float* ca_b1      = (const float*)d_in[3];
  const float* ca_w2      = (const float*)d_in[4];
  const float* ca_b2      = (const float*)d_in[5];
  const float* cls_dw     = (const float*)d_in[6];
  const float* cls_pw     = (const float*)d_in[7];
  const float* cls_bn_g   = (const float*)d_in[8];
  const float* cls_bn_b   = (const float*)d_in[9];
  const float* cls_bn_m   = (const float*)d_in[10];
  const float* cls_bn_v   = (const float*)d_in[11];
  const float* cls_pred_w = (const float*)d_in[12];
  const float* cls_pred_b = (const float*)d_in[13];
  const float* box_dw     = (const float*)d_in[14];
  const float* box_pw     = (const float*)d_in[15];
  const float* box_bn_g   = (const float*)d_in[16];
  const float* box_bn_b   = (const float*)d_in[17];
  const float* box_bn_m   = (const float*)d_in[18];
  const float* box_bn_v   = (const float*)d_in[19];
  const float* box_pred_w = (const float*)d_in[20];
  const float* box_pred_b = (const float*)d_in[21];
  const float* adjust     = (const float*)d_in[22];
  const float* bias_p     = (const float*)d_in[23];

  hipLaunchKernelGGL(fused_head, dim3(512), dim3(512), 0, stream,
    search, kern, ca_w1, ca_b1, ca_w2, ca_b2,
    cls_dw, cls_pw, cls_bn_g, cls_bn_b, cls_bn_m, cls_bn_v,
    cls_pred_w, cls_pred_b,
    box_dw, box_pw, box_bn_g, box_bn_b, box_bn_m, box_bn_v,
    box_pred_w, box_pred_b, adjust, bias_p,
    (float*)d_out);
}

// Round 17
// 68.404 us; speedup vs baseline: 1.2307x; 1.0769x over previous
//
#include <hip/hip_runtime.h>
#include <hip/hip_bf16.h>

// ---------------------------------------------------------------------------
// Fused SiamCAR head, FINAL (R12 restoration, 68.5us verified).
// Structure: grid 512 (one block/batch), 512 threads, 64KB LDS, 2 blocks/CU,
// exactly 1 dispatch round. corr GEMM via MFMA (single-bf16 z), channel
// attention folded into depthwise weights, sequential towers with the proven
// 2-barrier chunk loop, native HW bf16 converts. Spill-free at the (512,4)
// 64-arch/64-acc register split — six structural variants (concurrent
// towers, pipelined loops, DBUF, fused towers, all-lane MLP) all spilled or
// regressed; this is the converged configuration.
// LDS map:
//   corr phase : z 0-16K | stb [256pix][64c] 16K-48K | MLP scratch @49152
//   towers     : corr A 0-32K (RO) | d_T 32-64K -> bfr regs -> feat 32-48K |
//                pw dbuf @49152 | wA dbuf @57344 | BN @61952
// ---------------------------------------------------------------------------

typedef __attribute__((ext_vector_type(8))) short  bf16x8;
typedef __attribute__((ext_vector_type(4))) float  f32x4;

union U8 { bf16x8 v; uint4 q; unsigned short u[8]; };

__device__ __forceinline__ float bf2f(unsigned short h){
  union { unsigned int u; float f; } c; c.u = ((unsigned int)h) << 16; return c.f;
}
__device__ __forceinline__ unsigned short f2bf(float f){
  return __bfloat16_as_ushort(__float2bfloat16(f));   // HW cvt, RNE
}
__device__ __forceinline__ unsigned int f2bf2(float lo, float hi){
  return (unsigned int)f2bf(lo) | ((unsigned int)f2bf(hi) << 16);
}

// corr A tile [64 p][256 pix] bf16, elem index, 16B-chunk XOR swizzle.
__device__ __forceinline__ int swz(int row, int pix){
  return row*256 + (((pix>>3) ^ (row&31))<<3) + (pix&7);
}
// z^T tile [64 p][128 c] bf16, byte offset (256B rows, 16 chunks XOR by p).
__device__ __forceinline__ int zt_off(int p, int c){
  return (p<<8) + ((((c>>3) ^ (p&15)) & 15)<<4) + ((c&7)<<1);
}
// search^T chunk [256 pix][64 c] bf16, byte offset (128B rows, 8 chunks).
__device__ __forceinline__ int sT_off(int pix, int c){
  return (pix<<7) + ((((c>>3) ^ (pix&7) ^ ((pix>>3)&7)) & 7)<<4) + ((c&7)<<1);
}
// d_T [256 pix][64 p] bf16, byte offset.
__device__ __forceinline__ int dT_off(int pix, int p){
  return (pix<<7) + (((((p>>3) ^ pix) & 7)) << 4) + ((p & 7) << 1);
}
// feat_T [256 pix][32 ocl] bf16, byte offset.
__device__ __forceinline__ int fT_off(int pix, int ocl){
  return (pix<<6) + ((((ocl>>3) ^ pix ^ (pix>>2)) & 3) << 4) + ((ocl & 7) << 1);
}
// pw A-tile [32 ocl][64 p] bf16, byte offset.
__device__ __forceinline__ int pA_off(int ocl, int p){
  return (ocl<<7) + (((((p>>3) ^ ocl) & 7)) << 4) + ((p & 7) << 1);
}

// stage one 32-oc chunk of pw (fp32 global) -> [32][64] bf16 swizzled (512 thr)
__device__ __forceinline__ void stage_pw(int tid, int oc0,
                                         const float* __restrict__ pw,
                                         unsigned char* __restrict__ dst){
  const int ocl = tid >> 4, p0 = (tid & 15) << 2;
  const float4 f0 = *(const float4*)&pw[(oc0 + ocl)*64 + p0];
  uint2 w; w.x = f2bf2(f0.x, f0.y); w.y = f2bf2(f0.z, f0.w);
  *(uint2*)(dst + pA_off(ocl, p0)) = w;
}

// stage pred weights for one oc-chunk: wA[o][k = tau*32 + ocl] bf16 (512 thr)
template<int NOUT>
__device__ __forceinline__ void stage_wA(int tid, int oc0,
                                         const float* __restrict__ pdw,
                                         unsigned char* __restrict__ dst){
  #pragma unroll
  for (int i=0;i<(NOUT*288+511)/512;++i){
    const int idx = i*512 + tid;
    if (idx < NOUT*288){
      const int o   = idx / 288;
      const int rem = idx - o*288;
      const int tau = rem >> 5, ocl = rem & 31;
      *(unsigned short*)(dst + (idx<<1)) =
          f2bf(pdw[(o*256 + oc0 + ocl)*9 + tau]);
    }
  }
}

template<int NOUT>
__device__ __forceinline__ void run_tower(
    int tid, float ap,
    const float* __restrict__ dw,  const float* __restrict__ pw,
    const float* __restrict__ bng, const float* __restrict__ bnb,
    const float* __restrict__ bnm, const float* __restrict__ bnv,
    const float* __restrict__ pdw, const float* __restrict__ pdb,
    float* __restrict__ outp, float adj, const float* __restrict__ biasp,
    unsigned char* smem)
{
  const int lane = tid & 63, wave = tid >> 6;      // 8 waves
  const int l15 = lane & 15, lg = lane >> 4;
  unsigned short* sA16 = (unsigned short*)smem;    // corr A [64][256], RO

  // ---- depthwise 3x3 (pad 1), attention folded into weights, streamed;
  //      wave owns image rows 2w..2w+1; writes d_T @32768
  {
    const int p = lane;
    unsigned char* dT = smem + 32768;
    float wd[9];
    #pragma unroll
    for (int k=0;k<9;++k) wd[k] = dw[p*9+k] * ap;
    #pragma unroll
    for (int io=0;io<2;++io){
      const int ir = wave*2 + io;
      float ot[16];
      #pragma unroll
      for (int j=0;j<16;++j) ot[j] = 0.f;
      #pragma unroll
      for (int dr=0;dr<3;++dr){
        const int r = ir-1+dr;
        if (r >= 0 && r < 16){
          unsigned short tr[16];
          *(uint4*)&tr[0] = *(uint4*)&sA16[swz(p, r*16)];
          *(uint4*)&tr[8] = *(uint4*)&sA16[swz(p, r*16 + 8)];
          float rr[16];
          #pragma unroll
          for (int j=0;j<16;++j) rr[j] = bf2f(tr[j]);
          const float w0 = wd[dr*3+0], w1 = wd[dr*3+1], w2 = wd[dr*3+2];
          #pragma unroll
          for (int j=0;j<16;++j){
            float s = w1*rr[j];
            if (j > 0)  s = fmaf(w0, rr[j-1], s);
            if (j < 15) s = fmaf(w2, rr[j+1], s);
            ot[j] += s;
          }
        }
      }
      #pragma unroll
      for (int j=0;j<16;++j)
        *(unsigned short*)(dT + dT_off(ir*16+j, p)) = f2bf(ot[j]);
    }
  }
  __syncthreads();   // d_T complete (cross-lane handoff)

  // ---- pointwise B-operand chunk-invariant: cache wave's 32 pix in 16 VGPRs
  U8 bfr[2][2];
  #pragma unroll
  for (int nt=0;nt<2;++nt)
    #pragma unroll
    for (int ks=0;ks<2;++ks)
      bfr[nt][ks].q = *(const uint4*)(smem + 32768 +
          dT_off(wave*32 + nt*16 + l15, ks*32 + lg*8));
  __syncthreads();   // d_T dead; 32K-64K free for feat_T / staging

  // ---- BN scale/bias tables + chunk-0 weight staging
  float* scl = (float*)(smem + 61952);       // 256 f32
  float* bia = (float*)(smem + 62976);       // 256 f32
  if (tid < 256){
    const float s = bng[tid] * rsqrtf(bnv[tid] + 1e-5f);
    scl[tid] = s;
    bia[tid] = bnb[tid] - bnm[tid]*s;
  }
  stage_pw(tid, 0, pw, smem + 49152);
  stage_wA<NOUT>(tid, 0, pdw, smem + 57344);

  // pred accumulators: wave owns image rows 2w..2w+1; lane<16 reg r = out ch
  f32x4 accp[2];
  #pragma unroll
  for (int nt=0;nt<2;++nt) accp[nt] = f32x4{0.f,0.f,0.f,0.f};

  for (int ch=0; ch<8; ++ch){
    const int buf = ch & 1, oc0 = ch*32;
    __syncthreads();   // staged buf ready; prev pred finished reading feat_T

    // ---- pointwise via MFMA: feat[32 oc][256 pix] = pw(32x64) * d(64x256)
    unsigned char* pAb = smem + 49152 + buf*4096;
    U8 af[2][2];
    #pragma unroll
    for (int mt=0;mt<2;++mt)
      #pragma unroll
      for (int ks=0;ks<2;++ks)
        af[mt][ks].q = *(const uint4*)(pAb + pA_off(mt*16 + l15, ks*32 + lg*8));
    f32x4 accw[2][2];
    #pragma unroll
    for (int mt=0;mt<2;++mt)
      #pragma unroll
      for (int nt=0;nt<2;++nt) accw[mt][nt] = f32x4{0.f,0.f,0.f,0.f};
    #pragma unroll
    for (int nt=0;nt<2;++nt){
      #pragma unroll
      for (int mt=0;mt<2;++mt){
        accw[mt][nt] = __builtin_amdgcn_mfma_f32_16x16x32_bf16(
            af[mt][0].v, bfr[nt][0].v, accw[mt][nt], 0, 0, 0);
        accw[mt][nt] = __builtin_amdgcn_mfma_f32_16x16x32_bf16(
            af[mt][1].v, bfr[nt][1].v, accw[mt][nt], 0, 0, 0);
      }
    }
    // BN + ReLU -> feat_T [pix][32 ocl] bf16 @32768
    #pragma unroll
    for (int mt=0;mt<2;++mt){
      #pragma unroll
      for (int r=0;r<4;++r){
        const int ocl = mt*16 + lg*4 + r;
        const float sc = scl[oc0+ocl], bi = bia[oc0+ocl];
        #pragma unroll
        for (int nt=0;nt<2;++nt){
          const int pix = wave*32 + nt*16 + l15;
          const float v = fmaxf(fmaf(accw[mt][nt][r], sc, bi), 0.f);
          *(unsigned short*)(smem + 32768 + fT_off(pix, ocl)) = f2bf(v);
        }
      }
    }
    __syncthreads();   // feat_T chunk ready

    // ---- pred 3x3 partial via MFMA
    unsigned char* wAb = smem + 57344 + buf*2304;
    #pragma unroll
    for (int dr=0;dr<3;++dr){
      #pragma unroll
      for (int dc=0;dc<3;++dc){
        const int tau = dr*3 + dc;
        U8 a;
        const int mr = (NOUT == 4) ? (l15 & 3) : 0;
        a.q = *(const uint4*)(wAb + ((mr*288 + tau*32 + lg*8) << 1));
        if (l15 >= NOUT) a.q = make_uint4(0u,0u,0u,0u);
        #pragma unroll
        for (int nt=0;nt<2;++nt){
          const int rp = wave*2 + nt + dr - 1;      // uniform per wave
          if (rp >= 0 && rp <= 15){
            const int cp = l15 + dc - 1;
            const int cc = cp < 0 ? 0 : (cp > 15 ? 15 : cp);
            U8 bf;
            bf.q = *(const uint4*)(smem + 32768 + fT_off(rp*16 + cc, lg*8));
            if (cp != cc) bf.q = make_uint4(0u,0u,0u,0u);
            accp[nt] = __builtin_amdgcn_mfma_f32_16x16x32_bf16(
                a.v, bf.v, accp[nt], 0, 0, 0);
          }
        }
      }
    }
    // stage next chunk's weights (writes buf^1; no reader this phase)
    if (ch < 7){
      stage_pw(tid, oc0 + 32, pw, smem + 49152 + (buf^1)*4096);
      stage_wA<NOUT>(tid, oc0 + 32, pdw, smem + 57344 + (buf^1)*2304);
    }
  }

  // ---- epilogue: lanes 0-15 hold out-chs in regs; wave covers rows 2w..2w+1
  if (lane < 16){
    #pragma unroll
    for (int nt=0;nt<2;++nt){
      const int rt = wave*2 + nt;
      if constexpr (NOUT == 1){
        outp[rt*16 + lane] = 0.1f*(accp[nt][0] + pdb[0]);
      } else {
        #pragma unroll
        for (int o=0;o<4;++o)
          outp[o*256 + rt*16 + lane] =
              expf(fmaf(adj, accp[nt][o] + pdb[o], biasp[o]));
      }
    }
  }
  __syncthreads();   // feat_T/weight reads done before next tower's d_T write
}

__global__ __launch_bounds__(512, 4) void fused_head(
  const float* __restrict__ search, const float* __restrict__ kern,
  const float* __restrict__ ca_w1, const float* __restrict__ ca_b1,
  const float* __restrict__ ca_w2, const float* __restrict__ ca_b2,
  const float* __restrict__ cls_dw, const float* __restrict__ cls_pw,
  const float* __restrict__ cls_bn_g, const float* __restrict__ cls_bn_b,
  const float* __restrict__ cls_bn_m, const float* __restrict__ cls_bn_v,
  const float* __restrict__ cls_pred_w, const float* __restrict__ cls_pred_b,
  const float* __restrict__ box_dw, const float* __restrict__ box_pw,
  const float* __restrict__ box_bn_g, const float* __restrict__ box_bn_b,
  const float* __restrict__ box_bn_m, const float* __restrict__ box_bn_v,
  const float* __restrict__ box_pred_w, const float* __restrict__ box_pred_b,
  const float* __restrict__ adjust, const float* __restrict__ bias_p,
  float* __restrict__ out)
{
  __shared__ __align__(16) unsigned char smem[65536];
  const int b   = blockIdx.x;               // grid 512: one block per batch
  const int tid = threadIdx.x;
  const int lane = tid & 63, wave = tid >> 6;     // 8 waves
  const int l15 = lane & 15, lg = lane >> 4;

  // ---- stage z^T single-bf16 [64 p][128 c] swizzled @0 (16KB)
  unsigned char* zb = smem;
  {
    const float* kb = kern + (size_t)b*7168;       // [112 c][64 p]
    #pragma unroll
    for (int i=0;i<14;++i){
      const int idx = i*512 + tid;
      const int c = idx>>6, p = idx&63;
      *(unsigned short*)(zb + zt_off(p,c)) = f2bf(kb[idx]);
    }
    #pragma unroll
    for (int i=0;i<2;++i){                         // zero-pad c in [112,128)
      const int idx = i*512 + tid;
      const int p = idx>>4, c = 112 + (idx&15);
      *(unsigned short*)(zb + zt_off(p,c)) = 0;
    }
  }

  // ---- corr via MFMA: corr[64 p][256 pix] = z^T(64x112) * search(112x256)
  unsigned char* stb = smem + 16384;       // search^T chunk [256][64] bf16
  const float* sea = search + (size_t)b*28672;
  f32x4 acc[4][2];
  #pragma unroll
  for (int mt=0;mt<4;++mt)
    #pragma unroll
    for (int nt=0;nt<2;++nt) acc[mt][nt] = f32x4{0.f,0.f,0.f,0.f};

  for (int kc=0;kc<2;++kc){
    __syncthreads();                       // stb free (or z staging done)
    #pragma unroll
    for (int i=0;i<8;++i){
      const int f4i = i*512 + tid;
      const int cc = f4i>>6, pix0 = (f4i&63)<<2;
      const int c  = kc*64 + cc;
      float4 v;
      if (c < 112) v = *(const float4*)(sea + c*256 + pix0);
      else         v = make_float4(0.f,0.f,0.f,0.f);
      const float vv[4] = {v.x, v.y, v.z, v.w};
      #pragma unroll
      for (int j=0;j<4;++j)
        *(unsigned short*)(stb + sT_off(pix0+j, cc)) = f2bf(vv[j]);
    }
    __syncthreads();                       // chunk staged
    #pragma unroll
    for (int kt=0;kt<2;++kt){
      U8 bh[2];
      #pragma unroll
      for (int nt=0;nt<2;++nt){
        const int pix = wave*32 + nt*16 + l15;
        bh[nt].q = *(const uint4*)(stb + sT_off(pix, kt*32 + lg*8));
      }
      #pragma unroll
      for (int mt=0;mt<4;++mt){
        U8 ah;
        ah.q = *(const uint4*)(zb + zt_off(mt*16 + l15, kc*64 + kt*32 + lg*8));
        #pragma unroll
        for (int nt=0;nt<2;++nt)
          acc[mt][nt] = __builtin_amdgcn_mfma_f32_16x16x32_bf16(
              ah.v, bh[nt].v, acc[mt][nt], 0, 0, 0);
      }
    }
  }
  __syncthreads();                         // all LDS reads of z/stb drained

  // ---- stage corr UNSCALED bf16 [64][256] swizzled @0 (acc dies after MLP)
  unsigned short* sA16 = (unsigned short*)smem;
  #pragma unroll
  for (int mt=0;mt<4;++mt){
    #pragma unroll
    for (int nt=0;nt<2;++nt){
      const int pix = wave*32 + nt*16 + l15;
      #pragma unroll
      for (int r=0;r<4;++r)
        sA16[swz(mt*16 + lg*4 + r, pix)] = f2bf(acc[mt][nt][r]);
    }
  }

  // ---- row sums -> means + channel-attention MLP
  // scratch @49152.. (free during/after corr; dead before towers stage pw)
  float* ws    = (float*)(smem + 49152);          // [8][64] = 2048 B
  float* smean = (float*)(smem + 51200);          // 64 f32
  float* h1    = (float*)(smem + 51456);          // 64 f32
  float* attvG = (float*)(smem + 51712);          // 64 f32
  #pragma unroll
  for (int mt=0;mt<4;++mt){
    #pragma unroll
    for (int r=0;r<4;++r){
      float s = acc[mt][0][r] + acc[mt][1][r];
      s += __shfl_xor(s, 1, 64);
      s += __shfl_xor(s, 2, 64);
      s += __shfl_xor(s, 4, 64);
      s += __shfl_xor(s, 8, 64);
      if (l15 == 0) ws[wave*64 + mt*16 + lg*4 + r] = s;
    }
  }
  __syncthreads();
  if (tid < 64){
    float m = 0.f;
    #pragma unroll
    for (int w=0;w<8;++w) m += ws[w*64 + tid];
    smean[tid] = m * (1.f/256.f);
  }
  __syncthreads();
  if (tid < 64){
    float s = ca_b1[tid];
    const float* wr = ca_w1 + tid*64;
    #pragma unroll 8
    for (int k=0;k<64;++k) s += smean[k]*wr[k];
    h1[tid] = fmaxf(s, 0.f);
  }
  __syncthreads();
  if (tid < 64){
    float s = ca_b2[tid];
    const float* wr = ca_w2 + tid*64;
    #pragma unroll 8
    for (int k=0;k<64;++k) s += h1[k]*wr[k];
    attvG[tid] = 1.f/(1.f + expf(-s));
  }
  __syncthreads();               // attv ready
  const float ap = attvG[lane];
  __syncthreads();               // attv reads done before towers reuse @49152

  const float adj = adjust[0];

  run_tower<1>(tid, ap, cls_dw, cls_pw, cls_bn_g, cls_bn_b, cls_bn_m,
               cls_bn_v, cls_pred_w, cls_pred_b,
               out + 524288 + (size_t)b*256, adj, bias_p, smem);
  run_tower<4>(tid, ap, box_dw, box_pw, box_bn_g, box_bn_b, box_bn_m,
               box_bn_v, box_pred_w, box_pred_b,
               out + (size_t)b*1024, adj, bias_p, smem);
}

extern "C" void kernel_launch(void* const* d_in, const int* in_sizes, int n_in,
                              void* d_out, int out_size, void* d_ws, size_t ws_size,
                              hipStream_t stream) {
  (void)in_sizes; (void)n_in; (void)d_ws; (void)ws_size; (void)out_size;
  const float* search     = (const float*)d_in[0];
  const float* kern       = (const float*)d_in[1];
  const float* ca_w1      = (const float*)d_in[2];
  const float* ca_b1      = (const float*)d_in[3];
  const float* ca_w2      = (const float*)d_in[4];
  const float* ca_b2      = (const float*)d_in[5];
  const float* cls_dw     = (const float*)d_in[6];
  const float* cls_pw     = (const float*)d_in[7];
  const float* cls_bn_g   = (const float*)d_in[8];
  const float* cls_bn_b   = (const float*)d_in[9];
  const float* cls_bn_m   = (const float*)d_in[10];
  const float* cls_bn_v   = (const float*)d_in[11];
  const float* cls_pred_w = (const float*)d_in[12];
  const float* cls_pred_b = (const float*)d_in[13];
  const float* box_dw     = (const float*)d_in[14];
  const float* box_pw     = (const float*)d_in[15];
  const float* box_bn_g   = (const float*)d_in[16];
  const float* box_bn_b   = (const float*)d_in[17];
  const float* box_bn_m   = (const float*)d_in[18];
  const float* box_bn_v   = (const float*)d_in[19];
  const float* box_pred_w = (const float*)d_in[20];
  const float* box_pred_b = (const float*)d_in[21];
  const float* adjust     = (const float*)d_in[22];
  const float* bias_p     = (const float*)d_in[23];

  hipLaunchKernelGGL(fused_head, dim3(512), dim3(512), 0, stream,
    search, kern, ca_w1, ca_b1, ca_w2, ca_b2,
    cls_dw, cls_pw, cls_bn_g, cls_bn_b, cls_bn_m, cls_bn_v,
    cls_pred_w, cls_pred_b,
    box_dw, box_pw, box_bn_g, box_bn_b, box_bn_m, box_bn_v,
    box_pred_w, box_pred_b, adjust, bias_p,
    (float*)d_out);
}